// Round 10
// baseline (279.057 us; speedup 1.0000x reference)
//
#include <hip/hip_runtime.h>
#include <hip/hip_bf16.h>

#define SCALE 0.044194173824159216f

typedef float f32x4 __attribute__((ext_vector_type(4)));
typedef __bf16 bf16x8 __attribute__((ext_vector_type(8)));

static __device__ __forceinline__ unsigned short f2bf(float f){
  unsigned u = __builtin_bit_cast(unsigned, f);
  u += 0x7fffu + ((u >> 16) & 1u);
  return (unsigned short)(u >> 16);
}

// software grid barrier: one counter per phase boundary, zeroed by hipMemsetAsync each call.
// thread 0 arrives (device-scope add) and spins (device-scope load, s_sleep backoff, bounded).
static __device__ __forceinline__ void gbar(unsigned* bar, int e){
  __syncthreads();
  if (threadIdx.x == 0){
    __threadfence();                       // release: wb this XCD's L2
    __hip_atomic_fetch_add(&bar[e], 1u, __ATOMIC_ACQ_REL, __HIP_MEMORY_SCOPE_AGENT);
    unsigned spins = 0;
    while (__hip_atomic_load(&bar[e], __ATOMIC_ACQUIRE, __HIP_MEMORY_SCOPE_AGENT) < 256u){
      __builtin_amdgcn_s_sleep(2);
      if (++spins > (1u << 22)) break;     // bounded: fail loud, never hang
    }
  }
  __syncthreads();
  __threadfence();                         // acquire side for all threads (inv stale L1/L2)
}

__global__ __launch_bounds__(256) void mha_fused(
    const float* __restrict__ x, const int* __restrict__ mask,
    const float* __restrict__ w1q, const float* __restrict__ b1q,
    const float* __restrict__ w2q, const float* __restrict__ b2q,
    const float* __restrict__ w1k, const float* __restrict__ b1k,
    const float* __restrict__ w2k, const float* __restrict__ b2k,
    const float* __restrict__ w1v, const float* __restrict__ b1v,
    const float* __restrict__ w2v, const float* __restrict__ b2v,
    unsigned short* __restrict__ W1T, unsigned short* __restrict__ W2qT,
    float* __restrict__ Pm, unsigned short* __restrict__ Hq,
    float* __restrict__ part, float* __restrict__ At,
    unsigned short* __restrict__ GtA, float* __restrict__ Gbias,
    float* __restrict__ out, float* __restrict__ qout, unsigned* bar)
{
  __shared__ __attribute__((aligned(16))) char smem[51712];
  const int t = threadIdx.x, bid = blockIdx.x;
  const int lane = t & 63, wave = t >> 6;
  const int l15 = lane & 15, lg = lane >> 4, ks = lg * 8;

  // ---------------- Phase A (R6 kA verbatim; blocks 81..255 idle) ----------------
  if (bid < 64){
    #pragma unroll
    for (int s = 0; s < 8; s++){
      int id = s*16384 + bid*256 + t;
      if (id < 98304){
        int n = id >> 9, k = id & 511;
        int p = n >> 6, c = n & 63;
        const float* w1 = (p==0)? w1q : ((p==1)? w1k : w1v);
        W1T[id] = f2bf(w1[k*64 + c]);
      } else {
        int j = id - 98304;
        int e = j >> 6, r = j & 63;
        W2qT[j] = f2bf(w2q[r*512 + e]);
      }
    }
  } else if (bid < 81){
    int id = (bid - 64)*256 + t;
    if (id < 4225){
      int i = id / 65, j = id - i*65;
      const float* qi = (i < 64)? (w2q + i*512) : b2q;
      const float* kj = (j < 64)? (w2k + j*512) : b2k;
      float s = 0.f;
      for (int e = 0; e < 512; e += 4){
        float4 a = *(const float4*)(qi + e);
        float4 b = *(const float4*)(kj + e);
        s += a.x*b.x + a.y*b.y + a.z*b.z + a.w*b.w;
      }
      Pm[id] = s * SCALE;
    }
  }
  gbar(bar, 0);

  // ---------------- Phase B (R6 kB verbatim) ----------------
  {
    unsigned short (*Ax)[40] = (unsigned short(*)[40])smem;
    unsigned short (*Bt)[40] = (unsigned short(*)[40])(smem + 5120);
    float (*ak)[66] = (float(*)[66])smem;
    float (*av)[66] = (float(*)[66])(smem + 16896);
    const int r0 = bid * 64;
    f32x4 acc[12];
    #pragma unroll
    for (int j = 0; j < 12; j++) acc[j] = (f32x4){0.f,0.f,0.f,0.f};
    for (int k0 = 0; k0 < 512; k0 += 32){
      #pragma unroll
      for (int s = 0; s < 2; s++){
        int i = t + 256*s;
        int r = i >> 3, kq = (i & 7) * 4;
        float4 v = *(const float4*)(x + (size_t)(r0 + r)*512 + k0 + kq);
        ushort4 pk; pk.x = f2bf(v.x); pk.y = f2bf(v.y); pk.z = f2bf(v.z); pk.w = f2bf(v.w);
        *(ushort4*)&Ax[r][kq] = pk;
      }
      #pragma unroll
      for (int s = 0; s < 3; s++){
        int i = t + 256*s;
        int n = i >> 2, kq = (i & 3) * 8;
        *(uint4*)&Bt[n][kq] = *(const uint4*)(W1T + n*512 + k0 + kq);
      }
      __syncthreads();
      const int arow = (wave << 4) | l15;
      bf16x8 af = *(const bf16x8*)&Ax[arow][ks];
      #pragma unroll
      for (int j = 0; j < 12; j++){
        bf16x8 bf = *(const bf16x8*)&Bt[j*16 + l15][ks];
        acc[j] = __builtin_amdgcn_mfma_f32_16x16x32_bf16(af, bf, acc[j], 0, 0, 0);
      }
      __syncthreads();
    }
    int rowl[4]; float mrow[4];
    #pragma unroll
    for (int rg = 0; rg < 4; rg++){
      rowl[rg] = (wave << 4) + (lg << 2) + rg;
      mrow[rg] = (float)mask[r0 + rowl[rg]];
    }
    #pragma unroll
    for (int j = 0; j < 4; j++){
      int c = (j << 4) | l15;
      float bias = b1q[c];
      #pragma unroll
      for (int rg = 0; rg < 4; rg++)
        Hq[(size_t)(r0 + rowl[rg])*64 + c] = f2bf(acc[j][rg] + bias);
    }
    #pragma unroll
    for (int j = 0; j < 4; j++){
      int c = (j << 4) | l15;
      float bias = b1k[c];
      #pragma unroll
      for (int rg = 0; rg < 4; rg++)
        ak[rowl[rg]][c] = (acc[4 + j][rg] + bias) * mrow[rg];
    }
    #pragma unroll
    for (int j = 0; j < 4; j++){
      int c = (j << 4) | l15;
      float bias = b1v[c];
      #pragma unroll
      for (int rg = 0; rg < 4; rg++)
        av[rowl[rg]][c] = acc[8 + j][rg] + bias;
    }
    if (t < 64){ ak[t][64] = (float)mask[r0 + t]; av[t][64] = 1.f; }
    __syncthreads();
    if (t < 169){
      int tj = t / 13, ti = t - tj*13;
      int i0 = ti * 5, j0 = tj * 5;
      float pacc[5][5];
      #pragma unroll
      for (int a = 0; a < 5; a++)
        #pragma unroll
        for (int v = 0; v < 5; v++) pacc[a][v] = 0.f;
      for (int r = 0; r < 64; r++){
        float a[5], v[5];
        #pragma unroll
        for (int ii = 0; ii < 5; ii++) a[ii] = ak[r][i0 + ii];
        #pragma unroll
        for (int jj = 0; jj < 5; jj++) v[jj] = av[r][j0 + jj];
        #pragma unroll
        for (int ii = 0; ii < 5; ii++)
          #pragma unroll
          for (int jj = 0; jj < 5; jj++) pacc[ii][jj] += a[ii] * v[jj];
      }
      float* pout = part + (size_t)bid * 4225;
      #pragma unroll
      for (int ii = 0; ii < 5; ii++)
        #pragma unroll
        for (int jj = 0; jj < 5; jj++)
          pout[(i0 + ii)*65 + (j0 + jj)] = pacc[ii][jj];
    }
  }
  gbar(bar, 1);

  // ---------------- Phase R (R6 kR verbatim, full grid) ----------------
  {
    int g = bid*256 + t;
    if (g < 33800){
      int b = g / 4225, e = g - b*4225;
      const float* p = part + (size_t)b*135200 + e;
      float s = 0.f;
      #pragma unroll
      for (int ch = 0; ch < 32; ch++) s += p[(size_t)ch*4225];
      At[g] = s;
    }
  }
  gbar(bar, 2);

  // ---------------- Phase C (R6 k3b verbatim, blocks 0..63) ----------------
  if (bid < 64){
    float* Pl  = (float*)smem;
    float* Atl = Pl + 4290;
    float* T1l = Atl + 4290;
    const int b = bid >> 3, ec = (bid & 7) << 6;
    for (int id = t; id < 4225; id += 256){
      int i = id / 65, j = id - i*65;
      Pl[i*66 + j]  = Pm[id];
      Atl[i*66 + j] = At[(size_t)b*4225 + id];
    }
    __syncthreads();
    if (t < 169){
      int tj = t / 13, ti = t - tj*13;
      int i0 = ti * 5, j0 = tj * 5;
      float acc[5][5];
      #pragma unroll
      for (int a = 0; a < 5; a++)
        #pragma unroll
        for (int v = 0; v < 5; v++) acc[a][v] = 0.f;
      for (int k = 0; k < 65; k++){
        float a[5], vv[5];
        #pragma unroll
        for (int ii = 0; ii < 5; ii++) a[ii] = Pl[(i0 + ii)*66 + k];
        #pragma unroll
        for (int jj = 0; jj < 5; jj++) vv[jj] = Atl[k*66 + j0 + jj];
        #pragma unroll
        for (int ii = 0; ii < 5; ii++)
          #pragma unroll
          for (int jj = 0; jj < 5; jj++) acc[ii][jj] += a[ii] * vv[jj];
      }
      #pragma unroll
      for (int ii = 0; ii < 5; ii++)
        #pragma unroll
        for (int jj = 0; jj < 5; jj++) T1l[(i0 + ii)*66 + (j0 + jj)] = acc[ii][jj];
    }
    __syncthreads();
    for (int id = t; id < 4096; id += 256){
      int j = id >> 6, c = id & 63;
      Pl[j*66 + c] = w2v[j*512 + ec + c];
    }
    __syncthreads();
    if (t < 169){
      int tj = t / 13, ti = t - tj*13;
      int i0 = ti * 5, j0 = tj * 5;
      float acc[5][5];
      #pragma unroll
      for (int a = 0; a < 5; a++)
        #pragma unroll
        for (int v = 0; v < 5; v++) acc[a][v] = 0.f;
      for (int k = 0; k < 64; k++){
        float a[5], vv[5];
        #pragma unroll
        for (int ii = 0; ii < 5; ii++) a[ii] = T1l[(i0 + ii)*66 + k];
        #pragma unroll
        for (int jj = 0; jj < 5; jj++) vv[jj] = Pl[k*66 + j0 + jj];
        #pragma unroll
        for (int ii = 0; ii < 5; ii++)
          #pragma unroll
          for (int jj = 0; jj < 5; jj++) acc[ii][jj] += a[ii] * vv[jj];
      }
      #pragma unroll
      for (int ii = 0; ii < 5; ii++){
        int r = i0 + ii;
        float t64 = T1l[r*66 + 64];
        #pragma unroll
        for (int jj = 0; jj < 5; jj++){
          int ej = j0 + jj;
          if (ej < 64){
            int e = ec + ej;
            float s = acc[ii][jj] + t64 * b2v[e];
            if (r < 64) GtA[((size_t)b*512 + e)*64 + r] = f2bf(s);
            else        Gbias[b*512 + e] = s;
          }
        }
      }
    }
  }
  gbar(bar, 3);

  // ---------------- Phase E (R6 kD verbatim) ----------------
  {
    const int b = bid >> 5, rc = (bid & 31) << 6;
    const size_t gr0 = (size_t)b*2048 + rc;
    const int arow = (wave << 4) | l15;
    const unsigned short* arp = Hq + (gr0 + arow)*64 + ks;
    bf16x8 a0 = *(const bf16x8*)arp;
    bf16x8 a1 = *(const bf16x8*)(arp + 32);
    const unsigned short* Bsrc = GtA + (size_t)b*512*64;
    f32x4 acc[32];
    #pragma unroll
    for (int f = 0; f < 32; f++) acc[f] = (f32x4){0.f,0.f,0.f,0.f};
    #pragma unroll
    for (int f = 0; f < 32; f++){
      int col = (f << 4) | l15;
      bf16x8 b0 = *(const bf16x8*)(Bsrc + col*64 + ks);
      bf16x8 b1 = *(const bf16x8*)(Bsrc + col*64 + 32 + ks);
      acc[f] = __builtin_amdgcn_mfma_f32_16x16x32_bf16(a0, b0, acc[f], 0, 0, 0);
      acc[f] = __builtin_amdgcn_mfma_f32_16x16x32_bf16(a1, b1, acc[f], 0, 0, 0);
    }
    #pragma unroll
    for (int f = 0; f < 32; f++){
      float gbv = Gbias[(b << 9) | (f << 4) | l15];
      #pragma unroll
      for (int rg = 0; rg < 4; rg++) acc[f][rg] += gbv;
    }
    #pragma unroll
    for (int rg = 0; rg < 4; rg++){
      int row = rc + (wave << 4) + (lg << 2) + rg;
      float m = (float)mask[b*2048 + row];
      float mx = -3.4e38f;
      #pragma unroll
      for (int f = 0; f < 32; f++){
        float v = acc[f][rg] * m;
        acc[f][rg] = v;
        mx = fmaxf(mx, v);
      }
      #pragma unroll
      for (int d = 1; d < 16; d <<= 1) mx = fmaxf(mx, __shfl_xor(mx, d, 64));
      float sum = 0.f;
      #pragma unroll
      for (int f = 0; f < 32; f++){
        float ev = __expf(acc[f][rg] - mx);
        acc[f][rg] = ev;
        sum += ev;
      }
      #pragma unroll
      for (int d = 1; d < 16; d <<= 1) sum += __shfl_xor(sum, d, 64);
      float inv = 1.f / sum;
      float* orow = out + ((size_t)b*2048 + row) * 512;
      #pragma unroll
      for (int f = 0; f < 32; f++) orow[(f << 4) | l15] = acc[f][rg] * inv;
    }
    #pragma unroll
    for (int f = 0; f < 32; f++) acc[f] = (f32x4){0.f,0.f,0.f,0.f};
    #pragma unroll
    for (int f = 0; f < 32; f++){
      int col = (f << 4) | l15;
      bf16x8 b0 = *(const bf16x8*)(W2qT + col*64 + ks);
      bf16x8 b1 = *(const bf16x8*)(W2qT + col*64 + 32 + ks);
      acc[f] = __builtin_amdgcn_mfma_f32_16x16x32_bf16(a0, b0, acc[f], 0, 0, 0);
      acc[f] = __builtin_amdgcn_mfma_f32_16x16x32_bf16(a1, b1, acc[f], 0, 0, 0);
    }
    #pragma unroll
    for (int f = 0; f < 32; f++){
      int col = (f << 4) | l15;
      float bias = b2q[col];
      #pragma unroll
      for (int rg = 0; rg < 4; rg++){
        int row = rc + (wave << 4) + (lg << 2) + rg;
        qout[((size_t)b*2048 + row) * 512 + col] = acc[f][rg] + bias;
      }
    }
  }
}

extern "C" void kernel_launch(void* const* d_in, const int* in_sizes, int n_in,
                              void* d_out, int out_size, void* d_ws, size_t ws_size,
                              hipStream_t stream){
  const float* x    = (const float*)d_in[0];
  const int*   mask = (const int*)d_in[1];
  const float* q_w1 = (const float*)d_in[2];
  const float* q_b1 = (const float*)d_in[3];
  const float* q_w2 = (const float*)d_in[4];
  const float* q_b2 = (const float*)d_in[5];
  const float* k_w1 = (const float*)d_in[6];
  const float* k_b1 = (const float*)d_in[7];
  const float* k_w2 = (const float*)d_in[8];
  const float* k_b2 = (const float*)d_in[9];
  const float* v_w1 = (const float*)d_in[10];
  const float* v_b1 = (const float*)d_in[11];
  const float* v_w2 = (const float*)d_in[12];
  const float* v_b2 = (const float*)d_in[13];

  char* ws = (char*)d_ws;
  unsigned short* W1T  = (unsigned short*)(ws + 0);        // 196608
  unsigned short* W2qT = (unsigned short*)(ws + 196608);   // 65536 -> 262144
  float*          Pm   = (float*)(ws + 262144);            // 16900 -> pad 279296
  unsigned short* Hq   = (unsigned short*)(ws + 279296);   // 2097152 -> 2376448
  float*          part = (float*)(ws + 2376448);           // 256*4225*4 = 4326400 -> 6702848
  float*          At   = (float*)(ws + 6702848);           // 135200 -> pad 6838272
  unsigned short* GtA  = (unsigned short*)(ws + 6838272);  // 524288 -> 7362560
  float*          Gbias= (float*)(ws + 7362560);           // 16384 -> 7378944
  unsigned*       bar  = (unsigned*)(ws + 7378944);        // 16

  float* out  = (float*)d_out;
  float* qout = out + (size_t)8*2048*512;

  hipMemsetAsync(bar, 0, 4*sizeof(unsigned), stream);
  mha_fused<<<256, 256, 0, stream>>>(x, mask,
      q_w1, q_b1, q_w2, q_b2, k_w1, k_b1, k_w2, k_b2, v_w1, v_b1, v_w2, v_b2,
      W1T, W2qT, Pm, Hq, part, At, GtA, Gbias, out, qout, bar);
}

// Round 11
// 121.867 us; speedup vs baseline: 2.2898x; 2.2898x over previous
//
#include <hip/hip_runtime.h>
#include <hip/hip_bf16.h>

#define SCALE 0.044194173824159216f

typedef float f32x4 __attribute__((ext_vector_type(4)));
typedef __bf16 bf16x8 __attribute__((ext_vector_type(8)));

static __device__ __forceinline__ unsigned short f2bf(float f){
  unsigned u = __builtin_bit_cast(unsigned, f);
  u += 0x7fffu + ((u >> 16) & 1u);
  return (unsigned short)(u >> 16);
}

// kA: blocks 0..63: pack w1q|w1k|w1v transposed -> W1T bf16 [192][512]; w2q -> W2qT bf16 [512][64]
//     blocks 64..80: Pm = scale * Wq~ @ Wk~^T [65][65]
//     all blocks: zero At[8][4225] (accumulated atomically by kB)
__global__ __launch_bounds__(256) void kA(const float* __restrict__ w1q, const float* __restrict__ w1k,
    const float* __restrict__ w1v, const float* __restrict__ w2q, const float* __restrict__ b2q,
    const float* __restrict__ w2k, const float* __restrict__ b2k,
    unsigned short* __restrict__ W1T, unsigned short* __restrict__ W2qT, float* __restrict__ Pm,
    float* __restrict__ At){
  const int bid = blockIdx.x, t = threadIdx.x;
  for (int g = bid*256 + t; g < 33800; g += 81*256) At[g] = 0.f;
  if (bid < 64){
    #pragma unroll
    for (int s = 0; s < 8; s++){
      int id = s*16384 + bid*256 + t;
      if (id < 192*512){
        int n = id >> 9, k = id & 511;
        int p = n >> 6, c = n & 63;
        const float* w1 = (p==0)? w1q : ((p==1)? w1k : w1v);
        W1T[id] = f2bf(w1[k*64 + c]);
      } else {
        int j = id - 192*512;
        int e = j >> 6, r = j & 63;
        W2qT[j] = f2bf(w2q[r*512 + e]);
      }
    }
  } else {
    int id = (bid - 64)*256 + t;
    if (id >= 65*65) return;
    int i = id / 65, j = id - i*65;
    const float* qi = (i < 64)? (w2q + i*512) : b2q;
    const float* kj = (j < 64)? (w2k + j*512) : b2k;
    float s = 0.f;
    for (int e = 0; e < 512; e += 4){
      float4 a = *(const float4*)(qi + e);
      float4 b = *(const float4*)(kj + e);
      s += a.x*b.x; s += a.y*b.y; s += a.z*b.z; s += a.w*b.w;
    }
    Pm[id] = s * SCALE;
  }
}

// kB: H = x@w1+b1 (q,k,v) via MFMA (pre-packed W1T, uint4 reads); Hq -> global bf16;
//     Hk*m,Hv -> LDS fp32; partial Atil (65x65) atomicAdd -> At[b] (no part buffer, no kR).
__global__ __launch_bounds__(256) void kB(const float* __restrict__ x, const unsigned short* __restrict__ W1T,
    const float* __restrict__ b1q, const float* __restrict__ b1k, const float* __restrict__ b1v,
    const int* __restrict__ mask,
    unsigned short* __restrict__ Hq, float* __restrict__ At){
  __shared__ __attribute__((aligned(16))) char smem[33792];
  unsigned short (*Ax)[40] = (unsigned short(*)[40])smem;          // [64][40] bf16 (GEMM phase)
  unsigned short (*Bt)[40] = (unsigned short(*)[40])(smem + 5120); // [192][40] bf16 (GEMM phase)
  float (*ak)[66] = (float(*)[66])smem;                            // [64][66] fp32 (Atil phase)
  float (*av)[66] = (float(*)[66])(smem + 16896);                  // [64][66] fp32 (Atil phase)
  const int t = threadIdx.x;
  const int lane = t & 63, wave = t >> 6;
  const int l15 = lane & 15, lg = lane >> 4, ks = lg * 8;
  const int r0 = blockIdx.x * 64;
  f32x4 acc[12];
  #pragma unroll
  for (int j = 0; j < 12; j++) acc[j] = (f32x4){0.f,0.f,0.f,0.f};
  for (int k0 = 0; k0 < 512; k0 += 32){
    #pragma unroll
    for (int s = 0; s < 2; s++){           // stage A: 64 rows x 32 k (fp32->bf16)
      int i = t + 256*s;
      int r = i >> 3, kq = (i & 7) * 4;
      float4 v = *(const float4*)(x + (size_t)(r0 + r)*512 + k0 + kq);
      ushort4 pk; pk.x = f2bf(v.x); pk.y = f2bf(v.y); pk.z = f2bf(v.z); pk.w = f2bf(v.w);
      *(ushort4*)&Ax[r][kq] = pk;
    }
    #pragma unroll
    for (int s = 0; s < 3; s++){           // stage B: 192 cols x 32 k (bf16 n-major, uint4)
      int i = t + 256*s;
      int n = i >> 2, kq = (i & 3) * 8;
      *(uint4*)&Bt[n][kq] = *(const uint4*)(W1T + n*512 + k0 + kq);
    }
    __syncthreads();
    const int arow = (wave << 4) | l15;
    bf16x8 af = *(const bf16x8*)&Ax[arow][ks];
    #pragma unroll
    for (int j = 0; j < 12; j++){
      bf16x8 bf = *(const bf16x8*)&Bt[j*16 + l15][ks];
      acc[j] = __builtin_amdgcn_mfma_f32_16x16x32_bf16(af, bf, acc[j], 0, 0, 0);
    }
    __syncthreads();
  }
  // epilogue: Hq -> global, ak/av -> LDS (after final barrier)
  int rowl[4]; float mrow[4];
  #pragma unroll
  for (int rg = 0; rg < 4; rg++){
    rowl[rg] = (wave << 4) + (lg << 2) + rg;
    mrow[rg] = (float)mask[r0 + rowl[rg]];
  }
  #pragma unroll
  for (int j = 0; j < 4; j++){             // q -> global bf16
    int c = (j << 4) | l15;
    float bias = b1q[c];
    #pragma unroll
    for (int rg = 0; rg < 4; rg++)
      Hq[(size_t)(r0 + rowl[rg])*64 + c] = f2bf(acc[j][rg] + bias);
  }
  #pragma unroll
  for (int j = 0; j < 4; j++){             // k*m -> LDS fp32
    int c = (j << 4) | l15;
    float bias = b1k[c];
    #pragma unroll
    for (int rg = 0; rg < 4; rg++)
      ak[rowl[rg]][c] = (acc[4 + j][rg] + bias) * mrow[rg];
  }
  #pragma unroll
  for (int j = 0; j < 4; j++){             // v -> LDS fp32
    int c = (j << 4) | l15;
    float bias = b1v[c];
    #pragma unroll
    for (int rg = 0; rg < 4; rg++)
      av[rowl[rg]][c] = acc[8 + j][rg] + bias;
  }
  if (t < 64){ ak[t][64] = (float)mask[r0 + t]; av[t][64] = 1.f; }
  __syncthreads();
  if (t < 169){                            // partial Atil: 13x13 threads, 5x5 tiles
    int tj = t / 13, ti = t - tj*13;
    int i0 = ti * 5, j0 = tj * 5;
    float pacc[5][5];
    #pragma unroll
    for (int a = 0; a < 5; a++)
      #pragma unroll
      for (int v = 0; v < 5; v++) pacc[a][v] = 0.f;
    for (int r = 0; r < 64; r++){
      float a[5], v[5];
      #pragma unroll
      for (int ii = 0; ii < 5; ii++) a[ii] = ak[r][i0 + ii];
      #pragma unroll
      for (int jj = 0; jj < 5; jj++) v[jj] = av[r][j0 + jj];
      #pragma unroll
      for (int ii = 0; ii < 5; ii++)
        #pragma unroll
        for (int jj = 0; jj < 5; jj++) pacc[ii][jj] += a[ii] * v[jj];
    }
    float* aout = At + (size_t)(blockIdx.x >> 5) * 4225;   // batch accumulator
    #pragma unroll
    for (int ii = 0; ii < 5; ii++)
      #pragma unroll
      for (int jj = 0; jj < 5; jj++)
        atomicAdd(&aout[(i0 + ii)*65 + (j0 + jj)], pacc[ii][jj]);
  }
}

// k3b: T1 = P@At; G-chunk = T1@Wv~ -> GtA bf16 [b][512][64] + Gbias. grid = 8 b x 8 e-chunks
__global__ __launch_bounds__(256) void k3b(const float* __restrict__ At, const float* __restrict__ Pm,
    const float* __restrict__ w2v, const float* __restrict__ b2v,
    unsigned short* __restrict__ GtA, float* __restrict__ Gbias){
  __shared__ float Pl[65*66];
  __shared__ float Atl[65*66];
  __shared__ float T1l[65*66];
  const int t = threadIdx.x;
  const int b = blockIdx.x >> 3, ec = (blockIdx.x & 7) << 6;
  for (int id = t; id < 4225; id += 256){
    int i = id / 65, j = id - i*65;
    Pl[i*66 + j]  = Pm[id];
    Atl[i*66 + j] = At[(size_t)b*4225 + id];
  }
  __syncthreads();
  if (t < 169){                              // T1 = P @ Atl, 5x5 tiles
    int tj = t / 13, ti = t - tj*13;
    int i0 = ti * 5, j0 = tj * 5;
    float acc[5][5];
    #pragma unroll
    for (int a = 0; a < 5; a++)
      #pragma unroll
      for (int v = 0; v < 5; v++) acc[a][v] = 0.f;
    for (int k = 0; k < 65; k++){
      float a[5], vv[5];
      #pragma unroll
      for (int ii = 0; ii < 5; ii++) a[ii] = Pl[(i0 + ii)*66 + k];
      #pragma unroll
      for (int jj = 0; jj < 5; jj++) vv[jj] = Atl[k*66 + j0 + jj];
      #pragma unroll
      for (int ii = 0; ii < 5; ii++)
        #pragma unroll
        for (int jj = 0; jj < 5; jj++) acc[ii][jj] += a[ii] * vv[jj];
    }
    #pragma unroll
    for (int ii = 0; ii < 5; ii++)
      #pragma unroll
      for (int jj = 0; jj < 5; jj++) T1l[(i0 + ii)*66 + (j0 + jj)] = acc[ii][jj];
  }
  __syncthreads();
  for (int id = t; id < 4096; id += 256){    // stage Wv chunk into Pl (reuse)
    int j = id >> 6, c = id & 63;
    Pl[j*66 + c] = w2v[j*512 + ec + c];
  }
  __syncthreads();
  if (t < 169){                              // G = T1 @ Wl (+bias row)
    int tj = t / 13, ti = t - tj*13;
    int i0 = ti * 5, j0 = tj * 5;
    float acc[5][5];
    #pragma unroll
    for (int a = 0; a < 5; a++)
      #pragma unroll
      for (int v = 0; v < 5; v++) acc[a][v] = 0.f;
    for (int k = 0; k < 64; k++){
      float a[5], vv[5];
      #pragma unroll
      for (int ii = 0; ii < 5; ii++) a[ii] = T1l[(i0 + ii)*66 + k];
      #pragma unroll
      for (int jj = 0; jj < 5; jj++) vv[jj] = Pl[k*66 + j0 + jj];
      #pragma unroll
      for (int ii = 0; ii < 5; ii++)
        #pragma unroll
        for (int jj = 0; jj < 5; jj++) acc[ii][jj] += a[ii] * vv[jj];
    }
    #pragma unroll
    for (int ii = 0; ii < 5; ii++){
      int r = i0 + ii;
      float t64 = T1l[r*66 + 64];
      #pragma unroll
      for (int jj = 0; jj < 5; jj++){
        int ej = j0 + jj;
        if (ej < 64){
          int e = ec + ej;
          float s = acc[ii][jj] + t64 * b2v[e];
          if (r < 64) GtA[((size_t)b*512 + e)*64 + r] = f2bf(s);
          else        Gbias[b*512 + e] = s;
        }
      }
    }
  }
}

// kD: zero-LDS, zero-barrier. temp = m*(hq@G + Gbias) -> softmax -> out; q = hq@W2q~ -> qout.
__global__ __launch_bounds__(256) void kD(const unsigned short* __restrict__ Hq, const unsigned short* __restrict__ W2qT,
    const unsigned short* __restrict__ GtA, const float* __restrict__ Gbias, const float* __restrict__ b2q,
    const int* __restrict__ mask, float* __restrict__ out, float* __restrict__ qout){
  const int t = threadIdx.x, lane = t & 63, wave = t >> 6;
  const int b = blockIdx.x >> 5, rc = (blockIdx.x & 31) << 6;
  const int l15 = lane & 15, lg = lane >> 4, ks = lg * 8;
  const size_t gr0 = (size_t)b*2048 + rc;
  const int arow = (wave << 4) | l15;
  const unsigned short* arp = Hq + (gr0 + arow)*64 + ks;
  bf16x8 a0 = *(const bf16x8*)arp;
  bf16x8 a1 = *(const bf16x8*)(arp + 32);
  const unsigned short* Bsrc = GtA + (size_t)b*512*64;
  f32x4 acc[32];
  #pragma unroll
  for (int f = 0; f < 32; f++) acc[f] = (f32x4){0.f,0.f,0.f,0.f};
  #pragma unroll
  for (int f = 0; f < 32; f++){
    int col = (f << 4) | l15;
    bf16x8 b0 = *(const bf16x8*)(Bsrc + col*64 + ks);
    bf16x8 b1 = *(const bf16x8*)(Bsrc + col*64 + 32 + ks);
    acc[f] = __builtin_amdgcn_mfma_f32_16x16x32_bf16(a0, b0, acc[f], 0, 0, 0);
    acc[f] = __builtin_amdgcn_mfma_f32_16x16x32_bf16(a1, b1, acc[f], 0, 0, 0);
  }
  #pragma unroll
  for (int f = 0; f < 32; f++){
    float gbv = Gbias[(b << 9) | (f << 4) | l15];
    #pragma unroll
    for (int rg = 0; rg < 4; rg++) acc[f][rg] += gbv;
  }
  #pragma unroll
  for (int rg = 0; rg < 4; rg++){
    int row = rc + (wave << 4) + (lg << 2) + rg;
    float m = (float)mask[b*2048 + row];
    float mx = -3.4e38f;
    #pragma unroll
    for (int f = 0; f < 32; f++){
      float v = acc[f][rg] * m;
      acc[f][rg] = v;
      mx = fmaxf(mx, v);
    }
    #pragma unroll
    for (int d = 1; d < 16; d <<= 1) mx = fmaxf(mx, __shfl_xor(mx, d, 64));
    float sum = 0.f;
    #pragma unroll
    for (int f = 0; f < 32; f++){
      float ev = __expf(acc[f][rg] - mx);
      acc[f][rg] = ev;
      sum += ev;
    }
    #pragma unroll
    for (int d = 1; d < 16; d <<= 1) sum += __shfl_xor(sum, d, 64);
    float inv = 1.f / sum;
    float* orow = out + ((size_t)b*2048 + row) * 512;
    #pragma unroll
    for (int f = 0; f < 32; f++) orow[(f << 4) | l15] = acc[f][rg] * inv;
  }
  #pragma unroll
  for (int f = 0; f < 32; f++) acc[f] = (f32x4){0.f,0.f,0.f,0.f};
  #pragma unroll
  for (int f = 0; f < 32; f++){
    int col = (f << 4) | l15;
    bf16x8 b0 = *(const bf16x8*)(W2qT + col*64 + ks);
    bf16x8 b1 = *(const bf16x8*)(W2qT + col*64 + 32 + ks);
    acc[f] = __builtin_amdgcn_mfma_f32_16x16x32_bf16(a0, b0, acc[f], 0, 0, 0);
    acc[f] = __builtin_amdgcn_mfma_f32_16x16x32_bf16(a1, b1, acc[f], 0, 0, 0);
  }
  #pragma unroll
  for (int f = 0; f < 32; f++){
    int col = (f << 4) | l15;
    float bias = b2q[col];
    #pragma unroll
    for (int rg = 0; rg < 4; rg++){
      int row = rc + (wave << 4) + (lg << 2) + rg;
      qout[((size_t)b*2048 + row) * 512 + col] = acc[f][rg] + bias;
    }
  }
}

extern "C" void kernel_launch(void* const* d_in, const int* in_sizes, int n_in,
                              void* d_out, int out_size, void* d_ws, size_t ws_size,
                              hipStream_t stream){
  const float* x    = (const float*)d_in[0];
  const int*   mask = (const int*)d_in[1];
  const float* q_w1 = (const float*)d_in[2];
  const float* q_b1 = (const float*)d_in[3];
  const float* q_w2 = (const float*)d_in[4];
  const float* q_b2 = (const float*)d_in[5];
  const float* k_w1 = (const float*)d_in[6];
  const float* k_b1 = (const float*)d_in[7];
  const float* k_w2 = (const float*)d_in[8];
  const float* k_b2 = (const float*)d_in[9];
  const float* v_w1 = (const float*)d_in[10];
  const float* v_b1 = (const float*)d_in[11];
  const float* v_w2 = (const float*)d_in[12];
  const float* v_b2 = (const float*)d_in[13];

  char* ws = (char*)d_ws;
  unsigned short* W1T  = (unsigned short*)(ws + 0);        // 196608
  unsigned short* W2qT = (unsigned short*)(ws + 196608);   // 65536 -> 262144
  float*          Pm   = (float*)(ws + 262144);            // 16900 -> pad 279296
  unsigned short* Hq   = (unsigned short*)(ws + 279296);   // 2097152 -> 2376448
  float*          At   = (float*)(ws + 2376448);           // 135200 -> pad 2511872
  unsigned short* GtA  = (unsigned short*)(ws + 2511872);  // 524288 -> 3036160
  float*          Gbias= (float*)(ws + 3036160);           // 16384

  float* out  = (float*)d_out;
  float* qout = out + (size_t)8*2048*512;

  kA <<<81,  256, 0, stream>>>(q_w1, k_w1, v_w1, q_w2, q_b2, k_w2, k_b2, W1T, W2qT, Pm, At);
  kB <<<256, 256, 0, stream>>>(x, W1T, q_b1, k_b1, v_b1, mask, Hq, At);
  k3b<<<64,  256, 0, stream>>>(At, Pm, v_w2, v_b2, GtA, Gbias);
  kD <<<256, 256, 0, stream>>>(Hq, W2qT, GtA, Gbias, q_b2, mask, out, qout);
}

// Round 12
// 92.305 us; speedup vs baseline: 3.0232x; 1.3203x over previous
//
#include <hip/hip_runtime.h>
#include <hip/hip_bf16.h>

#define SCALE 0.044194173824159216f

typedef float f32x4 __attribute__((ext_vector_type(4)));
typedef __bf16 bf16x8 __attribute__((ext_vector_type(8)));

static __device__ __forceinline__ unsigned short f2bf(float f){
  unsigned u = __builtin_bit_cast(unsigned, f);
  u += 0x7fffu + ((u >> 16) & 1u);
  return (unsigned short)(u >> 16);
}
static __device__ __forceinline__ __bf16 f2bfv(float f){
  unsigned short s = f2bf(f);
  return __builtin_bit_cast(__bf16, s);
}

// kA: blocks 0..63: pack W1T bf16 [192][512]; W2qT bf16 [512][64]
//     blocks 64..80: Pm = scale * Wq~ @ Wk~^T [65][65]
//     blocks 81..82: Wvb bf16 [512 e][96 k]: k<64 = w2v[k][e], k=64 = b2v[e], k>64 = 0
__global__ __launch_bounds__(256) void kA(const float* __restrict__ w1q, const float* __restrict__ w1k,
    const float* __restrict__ w1v, const float* __restrict__ w2q, const float* __restrict__ b2q,
    const float* __restrict__ w2k, const float* __restrict__ b2k,
    const float* __restrict__ w2v, const float* __restrict__ b2v,
    unsigned short* __restrict__ W1T, unsigned short* __restrict__ W2qT, float* __restrict__ Pm,
    unsigned short* __restrict__ Wvb){
  const int bid = blockIdx.x, t = threadIdx.x;
  if (bid < 64){
    #pragma unroll
    for (int s = 0; s < 8; s++){
      int id = s*16384 + bid*256 + t;
      if (id < 192*512){
        int n = id >> 9, k = id & 511;
        int p = n >> 6, c = n & 63;
        const float* w1 = (p==0)? w1q : ((p==1)? w1k : w1v);
        W1T[id] = f2bf(w1[k*64 + c]);
      } else {
        int j = id - 192*512;
        int e = j >> 6, r = j & 63;
        W2qT[j] = f2bf(w2q[r*512 + e]);
      }
    }
  } else if (bid < 81){
    int id = (bid - 64)*256 + t;
    if (id < 65*65){
      int i = id / 65, j = id - i*65;
      const float* qi = (i < 64)? (w2q + i*512) : b2q;
      const float* kj = (j < 64)? (w2k + j*512) : b2k;
      float s = 0.f;
      for (int e = 0; e < 512; e += 4){
        float4 a = *(const float4*)(qi + e);
        float4 b = *(const float4*)(kj + e);
        s += a.x*b.x + a.y*b.y + a.z*b.z + a.w*b.w;
      }
      Pm[id] = s * SCALE;
    }
  } else {
    int e = (bid - 81)*256 + t;              // 0..511
    unsigned short* wp = Wvb + e*96;
    for (int k = 0; k < 64; k++) wp[k] = f2bf(w2v[k*512 + e]);
    wp[64] = f2bf(b2v[e]);
    #pragma unroll
    for (int k = 65; k < 96; k++) wp[k] = 0;
  }
}

// kB: H = x@w1+b1 (q,k,v) via MFMA; Hq -> global bf16; Hk*m,Hv -> LDS fp32;
//     partial Atil -> part[bid][stride 4228].  (R6/R8-verified)
__global__ __launch_bounds__(256) void kB(const float* __restrict__ x, const unsigned short* __restrict__ W1T,
    const float* __restrict__ b1q, const float* __restrict__ b1k, const float* __restrict__ b1v,
    const int* __restrict__ mask,
    unsigned short* __restrict__ Hq, float* __restrict__ part){
  __shared__ __attribute__((aligned(16))) char smem[33792];
  unsigned short (*Ax)[40] = (unsigned short(*)[40])smem;
  unsigned short (*Bt)[40] = (unsigned short(*)[40])(smem + 5120);
  float (*ak)[66] = (float(*)[66])smem;
  float (*av)[66] = (float(*)[66])(smem + 16896);
  const int t = threadIdx.x;
  const int lane = t & 63, wave = t >> 6;
  const int l15 = lane & 15, lg = lane >> 4, ks = lg * 8;
  const int r0 = blockIdx.x * 64;
  f32x4 acc[12];
  #pragma unroll
  for (int j = 0; j < 12; j++) acc[j] = (f32x4){0.f,0.f,0.f,0.f};
  for (int k0 = 0; k0 < 512; k0 += 32){
    #pragma unroll
    for (int s = 0; s < 2; s++){
      int i = t + 256*s;
      int r = i >> 3, kq = (i & 7) * 4;
      float4 v = *(const float4*)(x + (size_t)(r0 + r)*512 + k0 + kq);
      ushort4 pk; pk.x = f2bf(v.x); pk.y = f2bf(v.y); pk.z = f2bf(v.z); pk.w = f2bf(v.w);
      *(ushort4*)&Ax[r][kq] = pk;
    }
    #pragma unroll
    for (int s = 0; s < 3; s++){
      int i = t + 256*s;
      int n = i >> 2, kq = (i & 3) * 8;
      *(uint4*)&Bt[n][kq] = *(const uint4*)(W1T + n*512 + k0 + kq);
    }
    __syncthreads();
    const int arow = (wave << 4) | l15;
    bf16x8 af = *(const bf16x8*)&Ax[arow][ks];
    #pragma unroll
    for (int j = 0; j < 12; j++){
      bf16x8 bf = *(const bf16x8*)&Bt[j*16 + l15][ks];
      acc[j] = __builtin_amdgcn_mfma_f32_16x16x32_bf16(af, bf, acc[j], 0, 0, 0);
    }
    __syncthreads();
  }
  int rowl[4]; float mrow[4];
  #pragma unroll
  for (int rg = 0; rg < 4; rg++){
    rowl[rg] = (wave << 4) + (lg << 2) + rg;
    mrow[rg] = (float)mask[r0 + rowl[rg]];
  }
  #pragma unroll
  for (int j = 0; j < 4; j++){
    int c = (j << 4) | l15;
    float bias = b1q[c];
    #pragma unroll
    for (int rg = 0; rg < 4; rg++)
      Hq[(size_t)(r0 + rowl[rg])*64 + c] = f2bf(acc[j][rg] + bias);
  }
  #pragma unroll
  for (int j = 0; j < 4; j++){
    int c = (j << 4) | l15;
    float bias = b1k[c];
    #pragma unroll
    for (int rg = 0; rg < 4; rg++)
      ak[rowl[rg]][c] = (acc[4 + j][rg] + bias) * mrow[rg];
  }
  #pragma unroll
  for (int j = 0; j < 4; j++){
    int c = (j << 4) | l15;
    float bias = b1v[c];
    #pragma unroll
    for (int rg = 0; rg < 4; rg++)
      av[rowl[rg]][c] = acc[8 + j][rg] + bias;
  }
  if (t < 64){ ak[t][64] = (float)mask[r0 + t]; av[t][64] = 1.f; }
  __syncthreads();
  if (t < 169){
    int tj = t / 13, ti = t - tj*13;
    int i0 = ti * 5, j0 = tj * 5;
    float pacc[5][5];
    #pragma unroll
    for (int a = 0; a < 5; a++)
      #pragma unroll
      for (int v = 0; v < 5; v++) pacc[a][v] = 0.f;
    for (int r = 0; r < 64; r++){
      float a[5], v[5];
      #pragma unroll
      for (int ii = 0; ii < 5; ii++) a[ii] = ak[r][i0 + ii];
      #pragma unroll
      for (int jj = 0; jj < 5; jj++) v[jj] = av[r][j0 + jj];
      #pragma unroll
      for (int ii = 0; ii < 5; ii++)
        #pragma unroll
        for (int jj = 0; jj < 5; jj++) pacc[ii][jj] += a[ii] * v[jj];
    }
    float* pout = part + (size_t)blockIdx.x * 4228;
    #pragma unroll
    for (int ii = 0; ii < 5; ii++)
      #pragma unroll
      for (int jj = 0; jj < 5; jj++)
        pout[(i0 + ii)*65 + (j0 + jj)] = pacc[ii][jj];
  }
}

// kR: wide coalesced 32-way reduce part -> At[8][4225]
__global__ __launch_bounds__(256) void kR(const float* __restrict__ part, float* __restrict__ At){
  int g = blockIdx.x*256 + threadIdx.x;
  if (g < 33800){
    int b = g / 4225, e = g - b*4225;
    const float* p = part + (size_t)b*32*4228 + e;
    float s = 0.f;
    #pragma unroll
    for (int ch = 0; ch < 32; ch++) s += p[(size_t)ch*4228];
    At[g] = s;
  }
}

// kDT: per 64-row tile (absorbs k3b):
//   T1 = Pm @ At[b]  (in LDS, fp32, 169 threads 5x5)
//   stage1: temp1 = h~q @ T1  (MFMA; B-frags gathered from fp32 T1l, 2-way-conflict free)
//   stage2: temp = temp1 @ Wvb (k=96), *mask -> row softmax -> out
//   qout = hq @ W2qT + b2q
__global__ __launch_bounds__(256) void kDT(const unsigned short* __restrict__ Hq,
    const unsigned short* __restrict__ W2qT, const float* __restrict__ At,
    const float* __restrict__ Pm, const unsigned short* __restrict__ Wvb,
    const float* __restrict__ b2q, const int* __restrict__ mask,
    float* __restrict__ out, float* __restrict__ qout){
  __shared__ __attribute__((aligned(16))) char smem[51712];
  float* Pl  = (float*)smem;                   // [65][66]
  float* Atl = (float*)(smem + 17160);         // [65][66]
  float* T1l = (float*)(smem + 34320);         // [65][66]
  unsigned short (*t1l)[104] = (unsigned short(*)[104])smem;  // [64][104], overlays Pl/Atl after T1
  const int t = threadIdx.x, lane = t & 63, wave = t >> 6;
  const int b = blockIdx.x >> 5, rc = (blockIdx.x & 31) << 6;
  const int l15 = lane & 15, lg = lane >> 4, ks = lg * 8;
  const size_t gr0 = (size_t)b*2048 + rc;
  const int arow = (wave << 4) | l15;
  const unsigned short* arp = Hq + (gr0 + arow)*64 + ks;
  bf16x8 a0 = *(const bf16x8*)arp;
  bf16x8 a1 = *(const bf16x8*)(arp + 32);
  // ---- stage Pm + At[b] into LDS ----
  for (int id = t; id < 4225; id += 256){
    int i = id / 65, j = id - i*65;
    Pl[i*66 + j]  = Pm[id];
    Atl[i*66 + j] = At[(size_t)b*4225 + id];
  }
  __syncthreads();
  // ---- T1 = P @ At (fp32, 5x5 tiles) ----
  if (t < 169){
    int tj = t / 13, ti = t - tj*13;
    int i0 = ti * 5, j0 = tj * 5;
    float acc[5][5];
    #pragma unroll
    for (int a = 0; a < 5; a++)
      #pragma unroll
      for (int v = 0; v < 5; v++) acc[a][v] = 0.f;
    for (int k = 0; k < 65; k++){
      float a[5], vv[5];
      #pragma unroll
      for (int ii = 0; ii < 5; ii++) a[ii] = Pl[(i0 + ii)*66 + k];
      #pragma unroll
      for (int jj = 0; jj < 5; jj++) vv[jj] = Atl[k*66 + j0 + jj];
      #pragma unroll
      for (int ii = 0; ii < 5; ii++)
        #pragma unroll
        for (int jj = 0; jj < 5; jj++) acc[ii][jj] += a[ii] * vv[jj];
    }
    #pragma unroll
    for (int ii = 0; ii < 5; ii++)
      #pragma unroll
      for (int jj = 0; jj < 5; jj++) T1l[(i0 + ii)*66 + (j0 + jj)] = acc[ii][jj];
  }
  __syncthreads();
  // ---- stage 1: temp1 = h~q @ T1 (65 cols in 5 col-frags) ----
  f32x4 acc1[5];
  #pragma unroll
  for (int f = 0; f < 5; f++) acc1[f] = (f32x4){0.f,0.f,0.f,0.f};
  float trow[5];
  #pragma unroll
  for (int f = 0; f < 5; f++){
    int j = (f << 4) | l15;
    bf16x8 b0, b1;
    if (j < 65){
      #pragma unroll
      for (int idx = 0; idx < 8; idx++){
        b0[idx] = f2bfv(T1l[(ks + idx)*66 + j]);
        b1[idx] = f2bfv(T1l[(32 + ks + idx)*66 + j]);
      }
      trow[f] = T1l[64*66 + j];
    } else {
      #pragma unroll
      for (int idx = 0; idx < 8; idx++){ b0[idx] = f2bfv(0.f); b1[idx] = f2bfv(0.f); }
      trow[f] = 0.f;
    }
    acc1[f] = __builtin_amdgcn_mfma_f32_16x16x32_bf16(a0, b0, acc1[f], 0, 0, 0);
    acc1[f] = __builtin_amdgcn_mfma_f32_16x16x32_bf16(a1, b1, acc1[f], 0, 0, 0);
  }
  __syncthreads();                           // T1l reads done; smem reused as t1l
  // zero t1l cols 80..95
  *(ushort4*)&t1l[t >> 2][80 + ((t & 3) << 2)] = (ushort4){0,0,0,0};
  #pragma unroll
  for (int f = 0; f < 5; f++){
    int j = (f << 4) | l15;
    #pragma unroll
    for (int rg = 0; rg < 4; rg++)
      t1l[(wave << 4) + (lg << 2) + rg][j] = f2bf(acc1[f][rg] + trow[f]);
  }
  __syncthreads();
  // ---- stage 2: temp = temp1 @ Wvb, k=96 ----
  bf16x8 c0 = *(const bf16x8*)&t1l[arow][ks];
  bf16x8 c1 = *(const bf16x8*)&t1l[arow][32 + ks];
  bf16x8 c2 = *(const bf16x8*)&t1l[arow][64 + ks];
  f32x4 acc[32];
  #pragma unroll
  for (int f = 0; f < 32; f++) acc[f] = (f32x4){0.f,0.f,0.f,0.f};
  #pragma unroll
  for (int f = 0; f < 32; f++){
    int col = (f << 4) | l15;
    const unsigned short* wp = Wvb + col*96;
    bf16x8 b0 = *(const bf16x8*)(wp + ks);
    bf16x8 b1 = *(const bf16x8*)(wp + 32 + ks);
    bf16x8 b2 = *(const bf16x8*)(wp + 64 + ks);
    acc[f] = __builtin_amdgcn_mfma_f32_16x16x32_bf16(c0, b0, acc[f], 0, 0, 0);
    acc[f] = __builtin_amdgcn_mfma_f32_16x16x32_bf16(c1, b1, acc[f], 0, 0, 0);
    acc[f] = __builtin_amdgcn_mfma_f32_16x16x32_bf16(c2, b2, acc[f], 0, 0, 0);
  }
  #pragma unroll
  for (int rg = 0; rg < 4; rg++){
    int row = rc + (wave << 4) + (lg << 2) + rg;
    float m = (float)mask[b*2048 + row];
    float mx = -3.4e38f;
    #pragma unroll
    for (int f = 0; f < 32; f++){
      float v = acc[f][rg] * m;
      acc[f][rg] = v;
      mx = fmaxf(mx, v);
    }
    #pragma unroll
    for (int d = 1; d < 16; d <<= 1) mx = fmaxf(mx, __shfl_xor(mx, d, 64));
    float sum = 0.f;
    #pragma unroll
    for (int f = 0; f < 32; f++){
      float ev = __expf(acc[f][rg] - mx);
      acc[f][rg] = ev;
      sum += ev;
    }
    #pragma unroll
    for (int d = 1; d < 16; d <<= 1) sum += __shfl_xor(sum, d, 64);
    float inv = 1.f / sum;
    float* orow = out + ((size_t)b*2048 + row) * 512;
    #pragma unroll
    for (int f = 0; f < 32; f++) orow[(f << 4) | l15] = acc[f][rg] * inv;
  }
  // ---- qout = hq @ W2qT + b2q ----
  #pragma unroll
  for (int f = 0; f < 32; f++) acc[f] = (f32x4){0.f,0.f,0.f,0.f};
  #pragma unroll
  for (int f = 0; f < 32; f++){
    int col = (f << 4) | l15;
    bf16x8 b0 = *(const bf16x8*)(W2qT + col*64 + ks);
    bf16x8 b1 = *(const bf16x8*)(W2qT + col*64 + 32 + ks);
    acc[f] = __builtin_amdgcn_mfma_f32_16x16x32_bf16(a0, b0, acc[f], 0, 0, 0);
    acc[f] = __builtin_amdgcn_mfma_f32_16x16x32_bf16(a1, b1, acc[f], 0, 0, 0);
  }
  #pragma unroll
  for (int f = 0; f < 32; f++){
    int col = (f << 4) | l15;
    float bias = b2q[col];
    #pragma unroll
    for (int rg = 0; rg < 4; rg++){
      int row = rc + (wave << 4) + (lg << 2) + rg;
      qout[((size_t)b*2048 + row) * 512 + col] = acc[f][rg] + bias;
    }
  }
}

extern "C" void kernel_launch(void* const* d_in, const int* in_sizes, int n_in,
                              void* d_out, int out_size, void* d_ws, size_t ws_size,
                              hipStream_t stream){
  const float* x    = (const float*)d_in[0];
  const int*   mask = (const int*)d_in[1];
  const float* q_w1 = (const float*)d_in[2];
  const float* q_b1 = (const float*)d_in[3];
  const float* q_w2 = (const float*)d_in[4];
  const float* q_b2 = (const float*)d_in[5];
  const float* k_w1 = (const float*)d_in[6];
  const float* k_b1 = (const float*)d_in[7];
  const float* k_w2 = (const float*)d_in[8];
  const float* k_b2 = (const float*)d_in[9];
  const float* v_w1 = (const float*)d_in[10];
  const float* v_b1 = (const float*)d_in[11];
  const float* v_w2 = (const float*)d_in[12];
  const float* v_b2 = (const float*)d_in[13];

  char* ws = (char*)d_ws;
  unsigned short* W1T  = (unsigned short*)(ws + 0);        // 196608
  unsigned short* W2qT = (unsigned short*)(ws + 196608);   // 65536 -> 262144
  float*          Pm   = (float*)(ws + 262144);            // 16900 -> pad 279296
  unsigned short* Hq   = (unsigned short*)(ws + 279296);   // 2097152 -> 2376448
  float*          part = (float*)(ws + 2376448);           // 256*4228*4 = 4329472 -> 6705920
  float*          At   = (float*)(ws + 6705920);           // 135200 -> pad 6841344
  unsigned short* Wvb  = (unsigned short*)(ws + 6841344);  // 98304 -> 6939648

  float* out  = (float*)d_out;
  float* qout = out + (size_t)8*2048*512;

  kA <<<83,  256, 0, stream>>>(q_w1, k_w1, v_w1, q_w2, q_b2, k_w2, k_b2, v_w2, v_b2,
                               W1T, W2qT, Pm, Wvb);
  kB <<<256, 256, 0, stream>>>(x, W1T, q_b1, k_b1, v_b1, mask, Hq, part);
  kR <<<133, 256, 0, stream>>>(part, At);
  kDT<<<256, 256, 0, stream>>>(Hq, W2qT, At, Pm, Wvb, q_b2, mask, out, qout);
}

// Round 14
// 90.142 us; speedup vs baseline: 3.0958x; 1.0240x over previous
//
#include <hip/hip_runtime.h>
#include <hip/hip_bf16.h>

#define SCALE 0.044194173824159216f

typedef float f32x4 __attribute__((ext_vector_type(4)));
typedef __bf16 bf16x8 __attribute__((ext_vector_type(8)));

static __device__ __forceinline__ unsigned short f2bf(float f){
  unsigned u = __builtin_bit_cast(unsigned, f);
  u += 0x7fffu + ((u >> 16) & 1u);
  return (unsigned short)(u >> 16);
}

// kA: blocks 0..63: pack W1T bf16 [192][512]; W2qT bf16 [512][64]
//     blocks 64..80: Pm = scale * Wq~ @ Wk~^T [65][65]
//     blocks 81..82: Wvb bf16 [512 e][96 k]: k<64 = w2v[k][e], k=64 = b2v[e], k>64 = 0
__global__ __launch_bounds__(256) void kA(const float* __restrict__ w1q, const float* __restrict__ w1k,
    const float* __restrict__ w1v, const float* __restrict__ w2q, const float* __restrict__ b2q,
    const float* __restrict__ w2k, const float* __restrict__ b2k,
    const float* __restrict__ w2v, const float* __restrict__ b2v,
    unsigned short* __restrict__ W1T, unsigned short* __restrict__ W2qT, float* __restrict__ Pm,
    unsigned short* __restrict__ Wvb){
  const int bid = blockIdx.x, t = threadIdx.x;
  if (bid < 64){
    #pragma unroll
    for (int s = 0; s < 8; s++){
      int id = s*16384 + bid*256 + t;
      if (id < 192*512){
        int n = id >> 9, k = id & 511;
        int p = n >> 6, c = n & 63;
        const float* w1 = (p==0)? w1q : ((p==1)? w1k : w1v);
        W1T[id] = f2bf(w1[k*64 + c]);
      } else {
        int j = id - 192*512;
        int e = j >> 6, r = j & 63;
        W2qT[j] = f2bf(w2q[r*512 + e]);
      }
    }
  } else if (bid < 81){
    int id = (bid - 64)*256 + t;
    if (id < 65*65){
      int i = id / 65, j = id - i*65;
      const float* qi = (i < 64)? (w2q + i*512) : b2q;
      const float* kj = (j < 64)? (w2k + j*512) : b2k;
      float s = 0.f;
      for (int e = 0; e < 512; e += 4){
        float4 a = *(const float4*)(qi + e);
        float4 b = *(const float4*)(kj + e);
        s += a.x*b.x + a.y*b.y + a.z*b.z + a.w*b.w;
      }
      Pm[id] = s * SCALE;
    }
  } else {
    int e = (bid - 81)*256 + t;              // 0..511
    unsigned short* wp = Wvb + e*96;
    for (int k = 0; k < 64; k++) wp[k] = f2bf(w2v[k*512 + e]);
    wp[64] = f2bf(b2v[e]);
    #pragma unroll
    for (int k = 65; k < 96; k++) wp[k] = 0;
  }
}

// kB: H = x@w1+b1 (q,k,v) via MFMA; Hq -> global bf16; Hk*m,Hv -> LDS fp32;
//     partial Atil -> part CHUNK-MINOR: part[(b*4225 + i*65+j)*32 + ch]
__global__ __launch_bounds__(256) void kB(const float* __restrict__ x, const unsigned short* __restrict__ W1T,
    const float* __restrict__ b1q, const float* __restrict__ b1k, const float* __restrict__ b1v,
    const int* __restrict__ mask,
    unsigned short* __restrict__ Hq, float* __restrict__ part){
  __shared__ __attribute__((aligned(16))) char smem[33792];
  unsigned short (*Ax)[40] = (unsigned short(*)[40])smem;
  unsigned short (*Bt)[40] = (unsigned short(*)[40])(smem + 5120);
  float (*ak)[66] = (float(*)[66])smem;
  float (*av)[66] = (float(*)[66])(smem + 16896);
  const int t = threadIdx.x;
  const int lane = t & 63, wave = t >> 6;
  const int l15 = lane & 15, lg = lane >> 4, ks = lg * 8;
  const int r0 = blockIdx.x * 64;
  f32x4 acc[12];
  #pragma unroll
  for (int j = 0; j < 12; j++) acc[j] = (f32x4){0.f,0.f,0.f,0.f};
  for (int k0 = 0; k0 < 512; k0 += 32){
    #pragma unroll
    for (int s = 0; s < 2; s++){
      int i = t + 256*s;
      int r = i >> 3, kq = (i & 7) * 4;
      float4 v = *(const float4*)(x + (size_t)(r0 + r)*512 + k0 + kq);
      ushort4 pk; pk.x = f2bf(v.x); pk.y = f2bf(v.y); pk.z = f2bf(v.z); pk.w = f2bf(v.w);
      *(ushort4*)&Ax[r][kq] = pk;
    }
    #pragma unroll
    for (int s = 0; s < 3; s++){
      int i = t + 256*s;
      int n = i >> 2, kq = (i & 3) * 8;
      *(uint4*)&Bt[n][kq] = *(const uint4*)(W1T + n*512 + k0 + kq);
    }
    __syncthreads();
    const int arow = (wave << 4) | l15;
    bf16x8 af = *(const bf16x8*)&Ax[arow][ks];
    #pragma unroll
    for (int j = 0; j < 12; j++){
      bf16x8 bf = *(const bf16x8*)&Bt[j*16 + l15][ks];
      acc[j] = __builtin_amdgcn_mfma_f32_16x16x32_bf16(af, bf, acc[j], 0, 0, 0);
    }
    __syncthreads();
  }
  int rowl[4]; float mrow[4];
  #pragma unroll
  for (int rg = 0; rg < 4; rg++){
    rowl[rg] = (wave << 4) + (lg << 2) + rg;
    mrow[rg] = (float)mask[r0 + rowl[rg]];
  }
  #pragma unroll
  for (int j = 0; j < 4; j++){
    int c = (j << 4) | l15;
    float bias = b1q[c];
    #pragma unroll
    for (int rg = 0; rg < 4; rg++)
      Hq[(size_t)(r0 + rowl[rg])*64 + c] = f2bf(acc[j][rg] + bias);
  }
  #pragma unroll
  for (int j = 0; j < 4; j++){
    int c = (j << 4) | l15;
    float bias = b1k[c];
    #pragma unroll
    for (int rg = 0; rg < 4; rg++)
      ak[rowl[rg]][c] = (acc[4 + j][rg] + bias) * mrow[rg];
  }
  #pragma unroll
  for (int j = 0; j < 4; j++){
    int c = (j << 4) | l15;
    float bias = b1v[c];
    #pragma unroll
    for (int rg = 0; rg < 4; rg++)
      av[rowl[rg]][c] = acc[8 + j][rg] + bias;
  }
  if (t < 64){ ak[t][64] = (float)mask[r0 + t]; av[t][64] = 1.f; }
  __syncthreads();
  if (t < 169){
    int tj = t / 13, ti = t - tj*13;
    int i0 = ti * 5, j0 = tj * 5;
    float pacc[5][5];
    #pragma unroll
    for (int a = 0; a < 5; a++)
      #pragma unroll
      for (int v = 0; v < 5; v++) pacc[a][v] = 0.f;
    for (int r = 0; r < 64; r++){
      float a[5], v[5];
      #pragma unroll
      for (int ii = 0; ii < 5; ii++) a[ii] = ak[r][i0 + ii];
      #pragma unroll
      for (int jj = 0; jj < 5; jj++) v[jj] = av[r][j0 + jj];
      #pragma unroll
      for (int ii = 0; ii < 5; ii++)
        #pragma unroll
        for (int jj = 0; jj < 5; jj++) pacc[ii][jj] += a[ii] * v[jj];
    }
    float* pout = part + ((size_t)(blockIdx.x >> 5) * 4225) * 32 + (blockIdx.x & 31);
    #pragma unroll
    for (int ii = 0; ii < 5; ii++)
      #pragma unroll
      for (int jj = 0; jj < 5; jj++)
        pout[(size_t)((i0 + ii)*65 + (j0 + jj)) * 32] = pacc[ii][jj];
  }
}

// kRT1: fused reduce + T1, column-owned. grid = 8 batches x 17 col-chunks (4 cols each; last = 1).
//   BUGFIX vs R13: strided loops (nel=260 > 256 threads) so k=64 / i=64 items are processed.
__global__ __launch_bounds__(256) void kRT1(const float* __restrict__ part, const float* __restrict__ Pm,
    unsigned short* __restrict__ T1bt, float* __restrict__ T1r64){
  __shared__ float Pl[65*66];
  __shared__ float Avl[65*4];
  const int t = threadIdx.x;
  const int b = blockIdx.x / 17, jc = blockIdx.x - b*17;
  for (int id = t; id < 4225; id += 256){
    int i = id / 65, j = id - i*65;
    Pl[i*66 + j] = Pm[id];
  }
  const int ncol = (jc < 16) ? 4 : 1;
  const int j0 = jc * 4;
  const int nel = 65 * ncol;
  for (int z = t; z < nel; z += 256){
    int k = z / ncol, jj = z - k*ncol;
    const float* p = part + ((size_t)b*4225 + k*65 + (j0 + jj)) * 32;
    f32x4 s0 = *(const f32x4*)(p);       f32x4 s1 = *(const f32x4*)(p + 4);
    f32x4 s2 = *(const f32x4*)(p + 8);   f32x4 s3 = *(const f32x4*)(p + 12);
    s0 += *(const f32x4*)(p + 16); s1 += *(const f32x4*)(p + 20);
    s2 += *(const f32x4*)(p + 24); s3 += *(const f32x4*)(p + 28);
    f32x4 s = (s0 + s1) + (s2 + s3);
    Avl[k*4 + jj] = s[0] + s[1] + s[2] + s[3];
  }
  __syncthreads();
  unsigned short* Tb = T1bt + b*5120;
  float* Tr = T1r64 + b*80;
  for (int z = t; z < nel; z += 256){
    int i = z / ncol, jj = z - i*ncol;
    int j = j0 + jj;
    float s = 0.f;
    #pragma unroll 13
    for (int k = 0; k < 65; k++) s += Pl[i*66 + k] * Avl[k*4 + jj];
    if (i < 64) Tb[j*64 + i] = f2bf(s);
    else        Tr[j] = s;
  }
  if (jc == 16){
    for (int z = t; z < 255; z += 256){
      if (z < 240){
        int j = 65 + z/16, i4 = (z & 15) << 2;
        *(ushort4*)&Tb[j*64 + i4] = (ushort4){0,0,0,0};
      } else {
        Tr[65 + (z - 240)] = 0.f;
      }
    }
  }
}

// kD2 (R9-verified): per 64-row tile:
//   stage1: temp1 = hq @ T1 (+T1r64 row) -> LDS bf16 [64][104]
//   stage2: temp = temp1 @ Wvb (k=96), *mask -> row softmax -> out
//   qout = hq @ W2qT + b2q
__global__ __launch_bounds__(256) void kD2(const unsigned short* __restrict__ Hq,
    const unsigned short* __restrict__ W2qT, const unsigned short* __restrict__ T1bt,
    const float* __restrict__ T1r64, const unsigned short* __restrict__ Wvb,
    const float* __restrict__ b2q, const int* __restrict__ mask,
    float* __restrict__ out, float* __restrict__ qout){
  __shared__ __attribute__((aligned(16))) unsigned short t1l[64][104];
  const int t = threadIdx.x, lane = t & 63, wave = t >> 6;
  const int b = blockIdx.x >> 5, rc = (blockIdx.x & 31) << 6;
  const int l15 = lane & 15, lg = lane >> 4, ks = lg * 8;
  const size_t gr0 = (size_t)b*2048 + rc;
  const int arow = (wave << 4) | l15;
  const unsigned short* arp = Hq + (gr0 + arow)*64 + ks;
  bf16x8 a0 = *(const bf16x8*)arp;
  bf16x8 a1 = *(const bf16x8*)(arp + 32);
  const unsigned short* Tb = T1bt + b*5120;
  const float* Tr = T1r64 + b*80;
  f32x4 acc1[5];
  #pragma unroll
  for (int jf = 0; jf < 5; jf++) acc1[jf] = (f32x4){0.f,0.f,0.f,0.f};
  #pragma unroll
  for (int jf = 0; jf < 5; jf++){
    int col = (jf << 4) | l15;
    bf16x8 b0 = *(const bf16x8*)(Tb + col*64 + ks);
    bf16x8 b1 = *(const bf16x8*)(Tb + col*64 + 32 + ks);
    acc1[jf] = __builtin_amdgcn_mfma_f32_16x16x32_bf16(a0, b0, acc1[jf], 0, 0, 0);
    acc1[jf] = __builtin_amdgcn_mfma_f32_16x16x32_bf16(a1, b1, acc1[jf], 0, 0, 0);
  }
  *(ushort4*)&t1l[t >> 2][80 + ((t & 3) << 2)] = (ushort4){0,0,0,0};
  #pragma unroll
  for (int jf = 0; jf < 5; jf++){
    int col = (jf << 4) | l15;
    float tr = Tr[col];
    #pragma unroll
    for (int rg = 0; rg < 4; rg++)
      t1l[(wave << 4) + (lg << 2) + rg][col] = f2bf(acc1[jf][rg] + tr);
  }
  __syncthreads();
  bf16x8 c0 = *(const bf16x8*)&t1l[arow][ks];
  bf16x8 c1 = *(const bf16x8*)&t1l[arow][32 + ks];
  bf16x8 c2 = *(const bf16x8*)&t1l[arow][64 + ks];
  f32x4 acc[32];
  #pragma unroll
  for (int f = 0; f < 32; f++) acc[f] = (f32x4){0.f,0.f,0.f,0.f};
  #pragma unroll
  for (int f = 0; f < 32; f++){
    int col = (f << 4) | l15;
    const unsigned short* wp = Wvb + col*96;
    bf16x8 b0 = *(const bf16x8*)(wp + ks);
    bf16x8 b1 = *(const bf16x8*)(wp + 32 + ks);
    bf16x8 b2 = *(const bf16x8*)(wp + 64 + ks);
    acc[f] = __builtin_amdgcn_mfma_f32_16x16x32_bf16(c0, b0, acc[f], 0, 0, 0);
    acc[f] = __builtin_amdgcn_mfma_f32_16x16x32_bf16(c1, b1, acc[f], 0, 0, 0);
    acc[f] = __builtin_amdgcn_mfma_f32_16x16x32_bf16(c2, b2, acc[f], 0, 0, 0);
  }
  #pragma unroll
  for (int rg = 0; rg < 4; rg++){
    int row = rc + (wave << 4) + (lg << 2) + rg;
    float m = (float)mask[b*2048 + row];
    float mx = -3.4e38f;
    #pragma unroll
    for (int f = 0; f < 32; f++){
      float v = acc[f][rg] * m;
      acc[f][rg] = v;
      mx = fmaxf(mx, v);
    }
    #pragma unroll
    for (int d = 1; d < 16; d <<= 1) mx = fmaxf(mx, __shfl_xor(mx, d, 64));
    float sum = 0.f;
    #pragma unroll
    for (int f = 0; f < 32; f++){
      float ev = __expf(acc[f][rg] - mx);
      acc[f][rg] = ev;
      sum += ev;
    }
    #pragma unroll
    for (int d = 1; d < 16; d <<= 1) sum += __shfl_xor(sum, d, 64);
    float inv = 1.f / sum;
    float* orow = out + ((size_t)b*2048 + row) * 512;
    #pragma unroll
    for (int f = 0; f < 32; f++) orow[(f << 4) | l15] = acc[f][rg] * inv;
  }
  #pragma unroll
  for (int f = 0; f < 32; f++) acc[f] = (f32x4){0.f,0.f,0.f,0.f};
  #pragma unroll
  for (int f = 0; f < 32; f++){
    int col = (f << 4) | l15;
    bf16x8 b0 = *(const bf16x8*)(W2qT + col*64 + ks);
    bf16x8 b1 = *(const bf16x8*)(W2qT + col*64 + 32 + ks);
    acc[f] = __builtin_amdgcn_mfma_f32_16x16x32_bf16(a0, b0, acc[f], 0, 0, 0);
    acc[f] = __builtin_amdgcn_mfma_f32_16x16x32_bf16(a1, b1, acc[f], 0, 0, 0);
  }
  #pragma unroll
  for (int f = 0; f < 32; f++){
    int col = (f << 4) | l15;
    float bias = b2q[col];
    #pragma unroll
    for (int rg = 0; rg < 4; rg++){
      int row = rc + (wave << 4) + (lg << 2) + rg;
      qout[((size_t)b*2048 + row) * 512 + col] = acc[f][rg] + bias;
    }
  }
}

extern "C" void kernel_launch(void* const* d_in, const int* in_sizes, int n_in,
                              void* d_out, int out_size, void* d_ws, size_t ws_size,
                              hipStream_t stream){
  const float* x    = (const float*)d_in[0];
  const int*   mask = (const int*)d_in[1];
  const float* q_w1 = (const float*)d_in[2];
  const float* q_b1 = (const float*)d_in[3];
  const float* q_w2 = (const float*)d_in[4];
  const float* q_b2 = (const float*)d_in[5];
  const float* k_w1 = (const float*)d_in[6];
  const float* k_b1 = (const float*)d_in[7];
  const float* k_w2 = (const float*)d_in[8];
  const float* k_b2 = (const float*)d_in[9];
  const float* v_w1 = (const float*)d_in[10];
  const float* v_b1 = (const float*)d_in[11];
  const float* v_w2 = (const float*)d_in[12];
  const float* v_b2 = (const float*)d_in[13];

  char* ws = (char*)d_ws;
  unsigned short* W1T  = (unsigned short*)(ws + 0);        // 196608
  unsigned short* W2qT = (unsigned short*)(ws + 196608);   // 65536 -> 262144
  float*          Pm   = (float*)(ws + 262144);            // 16900 -> pad 279296
  unsigned short* Hq   = (unsigned short*)(ws + 279296);   // 2097152 -> 2376448
  float*          part = (float*)(ws + 2376448);           // 8*4225*32*4 = 4326400 -> 6702848
  unsigned short* Wvb  = (unsigned short*)(ws + 6702848);  // 98304 -> 6801152
  unsigned short* T1bt = (unsigned short*)(ws + 6801152);  // 81920 -> 6883072
  float*          T1r64= (float*)(ws + 6883072);           // 2560

  float* out  = (float*)d_out;
  float* qout = out + (size_t)8*2048*512;

  kA  <<<83,  256, 0, stream>>>(q_w1, k_w1, v_w1, q_w2, q_b2, k_w2, k_b2, v_w2, v_b2,
                                W1T, W2qT, Pm, Wvb);
  kB  <<<256, 256, 0, stream>>>(x, W1T, q_b1, k_b1, v_b1, mask, Hq, part);
  kRT1<<<136, 256, 0, stream>>>(part, Pm, T1bt, T1r64);
  kD2 <<<256, 256, 0, stream>>>(Hq, W2qT, T1bt, T1r64, Wvb, q_b2, mask, out, qout);
}